// Round 5
// baseline (234.454 us; speedup 1.0000x reference)
//
#include <hip/hip_runtime.h>

// Sparsemax over rows: B=131072, D=256, fp32.
//
// Persistent waves + 4-DEEP memory pipeline. Grid = 2048 blocks (8/CU,
// 32 waves/CU). Each wave owns 16 rows and keeps a 4-slot ring of row
// loads in flight: slot k's replacement load (row + 4*nw) is issued
// immediately after slot k's data is consumed, i.e. ~3 row-computes
// (~1500 cy) before it is needed. Up to 4 KB outstanding per wave (4x the
// previous 1-deep version) -- this is the memory-level-parallelism probe:
// rounds 0-4 all held ~1 row in flight per wave and all pinned at ~80 us
// with HBM at 31% and VALU at 28%, i.e. neither pipe saturated; the
// common factor was shallow MLP.
//
// Compute per row is the proven-cheapest form (round 4): DPP-only
// reductions (row_shr 1/2/4/8 + row_bcast 15/31, VALU pipe, no ds path),
// readlane(63) SGPR broadcast, Michelot from the tight superset
// A0 = {z > max-1} (valid since tau* in [max-1, max)), ballot+popcount
// convergence check BEFORE the sum reduce so the last iteration costs no
// reduction, and v_rcp for the small exact-int divide.

#define D_COLS 256

typedef float fvec4 __attribute__((ext_vector_type(4)));

// update_dpp(old, src, ctrl, row_mask, bank_mask, bound_ctrl=false):
// invalid source lanes receive `old` (the reduction identity).
#define DPP_MAX(v, ctrl)                                              \
  v = fmaxf(v, __int_as_float(__builtin_amdgcn_update_dpp(            \
                   (int)0xff800000 /* -inf */, __float_as_int(v),     \
                   ctrl, 0xF, 0xF, false)))
#define DPP_ADD(v, ctrl)                                              \
  v = v + __int_as_float(__builtin_amdgcn_update_dpp(                 \
              0 /* +0.0f */, __float_as_int(v), ctrl, 0xF, 0xF, false))

// ctrl: row_shr:1/2/4/8 = 0x111/0x112/0x114/0x118,
// row_bcast:15 = 0x142, row_bcast:31 = 0x143. Lane 63 ends with the total.
#define DPP_REDUCE_MAX(v)                                             \
  do {                                                                \
    DPP_MAX(v, 0x111); DPP_MAX(v, 0x112); DPP_MAX(v, 0x114);          \
    DPP_MAX(v, 0x118); DPP_MAX(v, 0x142); DPP_MAX(v, 0x143);          \
  } while (0)
#define DPP_REDUCE_ADD(v)                                             \
  do {                                                                \
    DPP_ADD(v, 0x111); DPP_ADD(v, 0x112); DPP_ADD(v, 0x114);          \
    DPP_ADD(v, 0x118); DPP_ADD(v, 0x142); DPP_ADD(v, 0x143);          \
  } while (0)

__device__ __forceinline__ void process_row(fvec4 v, float* __restrict__ outp) {
  // Row max -> initial tau = max - 1 (uniform via readlane/SGPR).
  float m = fmaxf(fmaxf(v.x, v.y), fmaxf(v.z, v.w));
  DPP_REDUCE_MAX(m);
  float tau =
      __int_as_float(__builtin_amdgcn_readlane(__float_as_int(m), 63)) - 1.0f;

  int prev = -1;  // impossible count => no break on first iteration
  for (int it = 0; it < 64; ++it) {
    unsigned long long b0 = __ballot(v.x > tau);
    unsigned long long b1 = __ballot(v.y > tau);
    unsigned long long b2 = __ballot(v.z > tau);
    unsigned long long b3 = __ballot(v.w > tau);
    const int c = __popcll(b0) + __popcll(b1) + __popcll(b2) + __popcll(b3);

    if (c == prev) break;  // active set stable => tau is the fixed point

    float ls = ((v.x > tau) ? v.x : 0.0f) + ((v.y > tau) ? v.y : 0.0f) +
               ((v.z > tau) ? v.z : 0.0f) + ((v.w > tau) ? v.w : 0.0f);
    DPP_REDUCE_ADD(ls);
    const float lsum =
        __int_as_float(__builtin_amdgcn_readlane(__float_as_int(ls), 63));

    // c is a small exact int: rcp rel-err ~1e-7, far under tolerance.
    tau = (lsum - 1.0f) * __builtin_amdgcn_rcpf((float)c);
    prev = c;
  }

  fvec4 o;
  o.x = fmaxf(v.x - tau, 0.0f);
  o.y = fmaxf(v.y - tau, 0.0f);
  o.z = fmaxf(v.z - tau, 0.0f);
  o.w = fmaxf(v.w - tau, 0.0f);
  *(fvec4*)outp = o;
}

__global__ __launch_bounds__(256) void sparsemax_kernel(
    const float* __restrict__ x, float* __restrict__ out, int nrows) {
  const int lane = threadIdx.x & 63;
  const int wid = blockIdx.x * 4 + (threadIdx.x >> 6);
  const int nw = gridDim.x * 4;  // waves; rows wid, wid+nw, ... belong to us
  if (wid >= nrows) return;

  const size_t rstride = (size_t)nw * D_COLS;          // floats between my rows
  const float* rp = x + (size_t)wid * D_COLS + lane * 4;
  float* wp = out + (size_t)wid * D_COLS + lane * 4;

  // Prime the 4-slot ring (named registers: no runtime indexing -> no scratch).
  fvec4 s0, s1, s2, s3;
  /* slot k holds row wid + (g*4+k)*nw for the current group g */
  s0 = *(const fvec4*)(rp);
  if (wid + 1 * nw < nrows) s1 = *(const fvec4*)(rp + 1 * rstride);
  if (wid + 2 * nw < nrows) s2 = *(const fvec4*)(rp + 2 * rstride);
  if (wid + 3 * nw < nrows) s3 = *(const fvec4*)(rp + 3 * rstride);

  for (int row = wid; row < nrows; row += 4 * nw) {
    const float* pf = rp + 4 * rstride;  // next group's loads
    // Slot 0: consume, immediately issue its replacement (3 computes ahead).
    {
      fvec4 v = s0;
      if (row + 4 * nw < nrows) s0 = *(const fvec4*)(pf);
      process_row(v, wp);
    }
    if (row + 1 * nw < nrows) {
      fvec4 v = s1;
      if (row + 5 * nw < nrows) s1 = *(const fvec4*)(pf + 1 * rstride);
      process_row(v, wp + 1 * rstride);
    }
    if (row + 2 * nw < nrows) {
      fvec4 v = s2;
      if (row + 6 * nw < nrows) s2 = *(const fvec4*)(pf + 2 * rstride);
      process_row(v, wp + 2 * rstride);
    }
    if (row + 3 * nw < nrows) {
      fvec4 v = s3;
      if (row + 7 * nw < nrows) s3 = *(const fvec4*)(pf + 3 * rstride);
      process_row(v, wp + 3 * rstride);
    }
    rp += 4 * rstride;
    wp += 4 * rstride;
  }
}

extern "C" void kernel_launch(void* const* d_in, const int* in_sizes, int n_in,
                              void* d_out, int out_size, void* d_ws, size_t ws_size,
                              hipStream_t stream) {
  const float* x = (const float*)d_in[0];
  float* out = (float*)d_out;
  const int nrows = in_sizes[0] / D_COLS;
  // 8 blocks/CU x 256 CUs: full residency; 131072/8192 = exactly 16 rows/wave.
  int blocks = 2048;
  const int max_blocks = (nrows + 3) / 4;
  if (blocks > max_blocks) blocks = max_blocks;
  sparsemax_kernel<<<blocks, 256, 0, stream>>>(x, out, nrows);
}

// Round 7
// 219.694 us; speedup vs baseline: 1.0672x; 1.0672x over previous
//
#include <hip/hip_runtime.h>

// Sparsemax over rows: B=131072, D=256, fp32.
// One 64-lane wave per row; each lane holds 4 contiguous elements (float4).
// tau via Michelot's algorithm started from the tight superset A0={z>max-1}
// (valid since tau* ∈ [max-1, max)): ~2-3 iterations for Gaussian rows vs
// ~6-8 from the full set. Convergence check (ballot count, scalar pipe) runs
// BEFORE the sum butterfly, so the final iteration costs no reduction.
//
// NOTE (rounds 1-6): 2-row ILP, half-wave rows, DPP-only reductions,
// persistent waves, and source-level / asm-level prefetch pipelines were all
// tried; every variant measured 80±3 µs at the dispatch level (asm pipeline
// crashed). Counters show no internal pipe above 42% (HBM 31%, VALU 28-42%,
// LDS 0). The dispatch floor tracks the harness's 512 MiB poison-fill whose
// dirty LLC lines drain to HBM during this kernel (~72 µs external floor).
// This version is the fastest measured; keep it.

#define D_COLS 256

__global__ __launch_bounds__(256) void sparsemax_kernel(
    const float* __restrict__ x, float* __restrict__ out, int nrows) {
  const int wave = threadIdx.x >> 6;
  const int lane = threadIdx.x & 63;
  const int row = blockIdx.x * 4 + wave;
  if (row >= nrows) return;

  const float4* rp = (const float4*)(x + (size_t)row * D_COLS);
  float4 v = rp[lane];

  // Row max -> initial tau = max - 1 (lower bound on tau*, superset start).
  float m = fmaxf(fmaxf(v.x, v.y), fmaxf(v.z, v.w));
  #pragma unroll
  for (int off = 32; off > 0; off >>= 1) m = fmaxf(m, __shfl_xor(m, off, 64));

  float tau = m - 1.0f;
  float prev_c = -1.0f;  // impossible count => no break on first iteration

  for (int it = 0; it < 64; ++it) {
    unsigned long long m0 = __ballot(v.x > tau);
    unsigned long long m1 = __ballot(v.y > tau);
    unsigned long long m2 = __ballot(v.z > tau);
    unsigned long long m3 = __ballot(v.w > tau);
    float c = (float)(__popcll(m0) + __popcll(m1) + __popcll(m2) + __popcll(m3));

    if (c == prev_c) break;  // active set stable => tau is the fixed point

    float ls = ((v.x > tau) ? v.x : 0.0f) + ((v.y > tau) ? v.y : 0.0f) +
               ((v.z > tau) ? v.z : 0.0f) + ((v.w > tau) ? v.w : 0.0f);
    #pragma unroll
    for (int off = 32; off > 0; off >>= 1) ls += __shfl_xor(ls, off, 64);

    tau = (ls - 1.0f) / c;
    prev_c = c;
  }

  float4 o;
  o.x = fmaxf(v.x - tau, 0.0f);
  o.y = fmaxf(v.y - tau, 0.0f);
  o.z = fmaxf(v.z - tau, 0.0f);
  o.w = fmaxf(v.w - tau, 0.0f);
  ((float4*)(out + (size_t)row * D_COLS))[lane] = o;
}

extern "C" void kernel_launch(void* const* d_in, const int* in_sizes, int n_in,
                              void* d_out, int out_size, void* d_ws, size_t ws_size,
                              hipStream_t stream) {
  const float* x = (const float*)d_in[0];
  float* out = (float*)d_out;
  const int nrows = in_sizes[0] / D_COLS;
  const int blocks = (nrows + 3) / 4;  // 4 rows (waves) per 256-thread block
  sparsemax_kernel<<<blocks, 256, 0, stream>>>(x, out, nrows);
}